// Round 3
// baseline (100.818 us; speedup 1.0000x reference)
//
#include <hip/hip_runtime.h>
#include <stdint.h>

// Problem constants
#define NTOT 8192   // B*(1+NPOS)
#define DD   128    // feature dim
#define BB   2048   // batch
#define NX   6144   // NPOS*B rows of x
// loss_neg subsample correction: log(4096/8191)
#define LOG_SUB_FRAC (-0.6930251f)
#define SQRT10 3.16227766017f
#define NBLK 2080   // 64*65/2 upper-tri tiles

typedef __attribute__((ext_vector_type(4))) float floatx4;  // MFMA C/D
typedef __attribute__((ext_vector_type(4))) int   intx4;
typedef __attribute__((ext_vector_type(8))) int   intx8;    // 32 B fp8 frag

#define GLOBAL_AS(p) ((const __attribute__((address_space(1))) void*)(p))
#define LDS_AS(p)    ((__attribute__((address_space(3))) void*)(p))

// DPP add: s + permuted(s). Row = 16 lanes on CDNA.
template <int CTRL>
__device__ __forceinline__ float dpp_add(float s) {
  return s + __int_as_float(
      __builtin_amdgcn_update_dpp(0, __float_as_int(s), CTRL, 0xF, 0xF, true));
}
// Sum across a 16-lane row (result in all 16 lanes): xor1, xor2, ror4, ror8.
__device__ __forceinline__ float row16_sum(float s) {
  s = dpp_add<0xB1>(s);   // quad_perm [1,0,3,2]
  s = dpp_add<0x4E>(s);   // quad_perm [2,3,0,1]
  s = dpp_add<0x124>(s);  // row_ror:4
  s = dpp_add<0x128>(s);  // row_ror:8
  return s;
}

// K1: L2-normalize rows of z = [x ; x_pair], scale by sqrt(10) (folds 1/TEMP
// into the MFMA so sim accumulates 10*cos directly) -> fp8 e4m3 (OCP).
// Fused positive dots (pure f32, unscaled). One wave per row.
// Zero-inits rowtotals[8192] and the K2 completion counter (stream-ordered;
// the K1->K2 kernel boundary flushes these plain stores to the coherent
// point before K2's atomics RMW them).
__global__ __launch_bounds__(256) void mp_norm(const float* __restrict__ x,
                                               const float* __restrict__ xp,
                                               uint8_t* __restrict__ znb8,
                                               float* __restrict__ pos,
                                               float* __restrict__ rowtotals,
                                               uint32_t* __restrict__ cnt) {
  const int z = blockIdx.x * 256 + threadIdx.x;
  if (z < NTOT) rowtotals[z] = 0.f;
  if (z == 0) *cnt = 0u;

  const int row  = blockIdx.x * 4 + (threadIdx.x >> 6);
  const int lane = threadIdx.x & 63;
  const bool isx = row < NX;
  const float* src = isx ? (x + (size_t)row * DD) : (xp + (size_t)(row - NX) * DD);
  float2 v = ((const float2*)src)[lane];
  float ss = v.x * v.x + v.y * v.y;

  float ssp = 0.f, d = 0.f;
  if (isx) {
    const int b = row & (BB - 1);
    float2 p = ((const float2*)(xp + (size_t)b * DD))[lane];
    ssp = p.x * p.x + p.y * p.y;
    d = v.x * p.x + v.y * p.y;
  }
  // wave-wide sums (all lanes get result)
  ss  = row16_sum(ss);  ss  += __shfl_xor(ss, 16, 64);  ss  += __shfl_xor(ss, 32, 64);
  if (isx) {
    ssp = row16_sum(ssp); ssp += __shfl_xor(ssp, 16, 64); ssp += __shfl_xor(ssp, 32, 64);
    d   = row16_sum(d);   d   += __shfl_xor(d, 16, 64);   d   += __shfl_xor(d, 32, 64);
  }
  const float rn = rsqrtf(ss);           // pure normalizer (for pos)
  const float rns = rn * SQRT10;         // scaled for znb8
  const int pk = __builtin_amdgcn_cvt_pk_fp8_f32(v.x * rns, v.y * rns, 0, false);
  *(uint16_t*)(znb8 + (size_t)row * DD + lane * 2) = (uint16_t)(pk & 0xffff);
  if (isx && lane == 0) pos[row] = d * rn * rsqrtf(ssp);
}

// K2: upper-triangle 128x128 tiles of 10*sim = Zs*Zs^T via MX-scaled fp8 MFMA
// (mfma_scale_f32_16x16x128_f8f6f4, fmt=e4m3, unit scales 0x7F -> x1.0):
// K=128 in ONE instruction at 2x non-scaled fp8 rate. LDS staging via
// global_load_lds (16 KB/tile), 16-B-pair XOR swizzle p^(row&7) (R2 lesson:
// direct-from-L2 frag loads cost +10 us — staging amortizes L2 LATENCY via
// one async drain/block + block-wide LDS reuse). 32 KB LDS, 4 blocks/CU.
// Epilogue: exp(acc) row+col sums -> atomicAdd rowtotals.
// Fused tail WITHOUT fences (R1 lesson: __threadfence = buffer_wbl2 L2-flush
// x2080 = 180 us). All cross-block data flows through device-scope atomics
// at the coherent point, so no dirty lines exist: per-wave s_waitcnt vmcnt(0)
// (atomics acked) + RELAXED counter + agent-scope tail loads suffice.
__global__ __launch_bounds__(256, 4) void mp_simexp(const uint8_t* __restrict__ znb8,
                                                    float* __restrict__ rowtotals,
                                                    const float* __restrict__ pos,
                                                    float* __restrict__ out,
                                                    uint32_t* __restrict__ cnt) {
  __shared__ uint8_t Asmem[128 * 128];
  __shared__ uint8_t Bsmem[128 * 128];
  __shared__ float rl[4], rp[4];
  __shared__ int lastflag;

  // Triangular decode: block t -> (bi, bj), bi <= bj.
  const int t = blockIdx.x;
  int bi = (int)((129.0f - sqrtf(16641.0f - 8.0f * (float)t)) * 0.5f);
  #define FCUM(r) ((r) * 64 - ((r) * ((r) - 1)) / 2)
  while (bi > 0 && FCUM(bi) > t) --bi;
  while (FCUM(bi + 1) <= t) ++bi;
  const int bj = bi + (t - FCUM(bi));
  const bool diag = (bi == bj);

  const int tid  = threadIdx.x;
  const int wave = tid >> 6, lane = tid & 63;
  const int lhi = lane >> 4, llo = lane & 15;

  const uint8_t* gA = znb8 + (size_t)bi * 128 * DD;
  const uint8_t* gB = znb8 + (size_t)bj * 128 * DD;

  // Stage tiles (16 KB each), 16 B/lane. Each wave-instr covers 8 rows
  // (128 B/row); lane l -> row c*8+(l>>3), 16-B pair p = (l&7)^(row&7)
  // (global source swizzled; LDS dest stays lane-contiguous). Diag: A only.
  #pragma unroll
  for (int tc = 0; tc < 4; ++tc) {
    const int c = wave * 4 + tc;
    const int row = c * 8 + (lane >> 3);
    const int p = (lane & 7) ^ (row & 7);
    const int roff = row * DD + p * 16;
    __builtin_amdgcn_global_load_lds(GLOBAL_AS(gA + roff), LDS_AS(&Asmem[c * 1024]), 16, 0, 0);
    if (!diag)
      __builtin_amdgcn_global_load_lds(GLOBAL_AS(gB + roff), LDS_AS(&Bsmem[c * 1024]), 16, 0, 0);
  }
  __syncthreads();
  const uint8_t* Bs = diag ? Asmem : Bsmem;

  // 2x2 wave grid; each wave computes a 64x64 subtile = 4x4 MFMA tiles,
  // one K=128 MFMA each. Frag: lane(llo=row, lhi): 32 contiguous K bytes at
  // lhi*32 = swizzled 16-B pairs (2*lhi)^(row&7), (2*lhi+1)^(row&7).
  // K-permutation invariance: A/B frags use identical addressing from
  // identically-laid-out tiles, so internal K ordering cancels in Z*Z^T.
  const int wr = wave >> 1, wc = wave & 1;
  floatx4 acc[4][4] = {};
  intx8 bfrag[4];
  #pragma unroll
  for (int c = 0; c < 4; ++c) {
    const int row = wc * 64 + c * 16 + llo;
    const uint8_t* base = Bs + row * DD;
    intx4 lo = *(const intx4*)(base + (((2 * lhi)     ^ (row & 7)) << 4));
    intx4 hi = *(const intx4*)(base + (((2 * lhi + 1) ^ (row & 7)) << 4));
    bfrag[c] = intx8{lo.x, lo.y, lo.z, lo.w, hi.x, hi.y, hi.z, hi.w};
  }
  #pragma unroll
  for (int r = 0; r < 4; ++r) {
    const int row = wr * 64 + r * 16 + llo;
    const uint8_t* base = Asmem + row * DD;
    intx4 lo = *(const intx4*)(base + (((2 * lhi)     ^ (row & 7)) << 4));
    intx4 hi = *(const intx4*)(base + (((2 * lhi + 1) ^ (row & 7)) << 4));
    intx8 afrag = intx8{lo.x, lo.y, lo.z, lo.w, hi.x, hi.y, hi.z, hi.w};
    #pragma unroll
    for (int c = 0; c < 4; ++c)
      acc[r][c] = __builtin_amdgcn_mfma_scale_f32_16x16x128_f8f6f4(
          afrag, bfrag[c], acc[r][c], 0, 0, 0, 0x7F7F7F7F, 0, 0x7F7F7F7F);
  }

  // Epilogue: e = exp(acc) (acc is already 10*cos); diag masked on the 64
  // diagonal blocks only (uniform branch). Row sums + col sums.
  // C/D layout: col = lane&15, row = (lane>>4)*4 + reg.
  float rowacc[4][4];
  #pragma unroll
  for (int r = 0; r < 4; ++r)
    #pragma unroll
    for (int j = 0; j < 4; ++j) rowacc[r][j] = 0.f;
  float colacc[4] = {0.f, 0.f, 0.f, 0.f};

  if (diag) {
    #pragma unroll
    for (int r = 0; r < 4; ++r) {
      #pragma unroll
      for (int c = 0; c < 4; ++c) {
        const int col = wc * 64 + c * 16 + llo;
        #pragma unroll
        for (int j = 0; j < 4; ++j) {
          const int row = wr * 64 + r * 16 + lhi * 4 + j;
          float e = __expf(acc[r][c][j]);
          if (row == col) e = 0.f;
          rowacc[r][j] += e;
          colacc[c] += e;
        }
      }
    }
  } else {
    #pragma unroll
    for (int r = 0; r < 4; ++r) {
      #pragma unroll
      for (int c = 0; c < 4; ++c) {
        #pragma unroll
        for (int j = 0; j < 4; ++j) {
          float e = __expf(acc[r][c][j]);
          rowacc[r][j] += e;
          colacc[c] += e;
        }
      }
    }
  }

  // Row sums: DPP-reduce across llo; lane llo==j issues the atomic for reg j.
  float* rowdst = rowtotals + bi * 128 + wr * 64;
  #pragma unroll
  for (int r = 0; r < 4; ++r) {
    #pragma unroll
    for (int j = 0; j < 4; ++j) {
      float s = row16_sum(rowacc[r][j]);
      if (llo == j) atomicAdd(&rowdst[r * 16 + lhi * 4 + j], s);
    }
  }
  // Col sums (skip on diag: rows already fully counted by rowsums there).
  if (!diag) {
    float* coldst = rowtotals + bj * 128 + wc * 64;
    #pragma unroll
    for (int c = 0; c < 4; ++c) {
      float s = colacc[c];
      s += __shfl_xor(s, 16, 64);
      s += __shfl_xor(s, 32, 64);
      if (lhi == 0) atomicAdd(&coldst[c * 16 + llo], s);  // 16 lanes, coalesced
    }
  }

  // ---- fused tail: last block computes the final scalar. NO FENCES. ----
  // Per-wave drain: this wave's atomicAdds are acked at the coherent point.
  asm volatile("s_waitcnt vmcnt(0)" ::: "memory");
  __syncthreads();  // all 4 waves' atomics drained
  if (tid == 0) {
    uint32_t old = __hip_atomic_fetch_add(cnt, 1u, __ATOMIC_RELAXED,
                                          __HIP_MEMORY_SCOPE_AGENT);
    lastflag = (old == NBLK - 1);
  }
  __syncthreads();
  if (!lastflag) return;

  // 256 threads: 32 row-logs + 24 pos reads each. Agent-scope atomic loads
  // of rowtotals read the coherent point (rows only ever touched by atomics
  // after the K1->K2 boundary flushed the zero-init).
  float l = 0.f;
  #pragma unroll
  for (int k = 0; k < 32; ++k) {
    float v = __hip_atomic_load(&rowtotals[k * 256 + tid], __ATOMIC_RELAXED,
                                __HIP_MEMORY_SCOPE_AGENT);
    l += logf(v);
  }
  float p = 0.f;
  #pragma unroll
  for (int k = 0; k < 24; ++k) p += pos[k * 256 + tid];
  #pragma unroll
  for (int m = 1; m < 64; m <<= 1) {
    l += __shfl_xor(l, m, 64);
    p += __shfl_xor(p, m, 64);
  }
  if ((tid & 63) == 0) { rl[tid >> 6] = l; rp[tid >> 6] = p; }
  __syncthreads();
  if (tid == 0) {
    const float S = rl[0] + rl[1] + rl[2] + rl[3];
    const float P = rp[0] + rp[1] + rp[2] + rp[3];
    const float loss_neg = S / (float)NTOT + LOG_SUB_FRAC;
    const float loss_pos = P * (10.0f / (float)NX);  // WEIGHT * (1/TEMP) / (B*NPOS)
    out[0] = loss_neg - loss_pos;
  }
}

extern "C" void kernel_launch(void* const* d_in, const int* in_sizes, int n_in,
                              void* d_out, int out_size, void* d_ws, size_t ws_size,
                              hipStream_t stream) {
  const float* x  = (const float*)d_in[0];   // [6144, 128] f32
  const float* xp = (const float*)d_in[1];   // [2048, 128] f32
  float* out = (float*)d_out;                // scalar f32

  char* ws = (char*)d_ws;
  uint8_t* znb8    = (uint8_t*)ws;                              // 1 MB
  float* pos       = (float*)(ws + (1u << 20));                 // 24 KB
  float* rowtotals = (float*)(ws + (1u << 20) + (32u << 10));   // 32 KB
  uint32_t* cnt    = (uint32_t*)(ws + (1u << 20) + (64u << 10));

  mp_norm<<<NTOT / 4, 256, 0, stream>>>(x, xp, znb8, pos, rowtotals, cnt);
  mp_simexp<<<NBLK, 256, 0, stream>>>(znb8, rowtotals, pos, out, cnt);
}

// Round 4
// 82.290 us; speedup vs baseline: 1.2251x; 1.2251x over previous
//
#include <hip/hip_runtime.h>
#include <stdint.h>

// Problem constants
#define NTOT 8192   // B*(1+NPOS)
#define DD   128    // feature dim
#define BB   2048   // batch
#define NX   6144   // NPOS*B rows of x
// loss_neg subsample correction: log(4096/8191)
#define LOG_SUB_FRAC (-0.6930251f)
#define SQRT10 3.16227766017f
#define NBLK 2080   // 64*65/2 upper-tri tiles
#define NPAN 64     // 128-row panels

typedef __attribute__((ext_vector_type(4))) float floatx4;  // MFMA C/D
typedef __attribute__((ext_vector_type(4))) int   intx4;
typedef __attribute__((ext_vector_type(8))) int   intx8;    // 32 B fp8 frag

#define GLOBAL_AS(p) ((const __attribute__((address_space(1))) void*)(p))
#define LDS_AS(p)    ((__attribute__((address_space(3))) void*)(p))

// DPP add: s + permuted(s). Row = 16 lanes on CDNA.
template <int CTRL>
__device__ __forceinline__ float dpp_add(float s) {
  return s + __int_as_float(
      __builtin_amdgcn_update_dpp(0, __float_as_int(s), CTRL, 0xF, 0xF, true));
}
// Sum across a 16-lane row (result in all 16 lanes): xor1, xor2, ror4, ror8.
__device__ __forceinline__ float row16_sum(float s) {
  s = dpp_add<0xB1>(s);   // quad_perm [1,0,3,2]
  s = dpp_add<0x4E>(s);   // quad_perm [2,3,0,1]
  s = dpp_add<0x124>(s);  // row_ror:4
  s = dpp_add<0x128>(s);  // row_ror:8
  return s;
}

// K1: L2-normalize rows of z = [x ; x_pair], scale by sqrt(10) (folds 1/TEMP
// into the MFMA so sim accumulates 10*cos directly) -> fp8 e4m3 (OCP).
// Fused positive dots (pure f32, unscaled). One wave per row.
// Zero-inits the K3 accumulators/counter (stream-ordered flush at boundary).
__global__ __launch_bounds__(256) void mp_norm(const float* __restrict__ x,
                                               const float* __restrict__ xp,
                                               uint8_t* __restrict__ znb8,
                                               float* __restrict__ pos,
                                               float* __restrict__ accs,
                                               uint32_t* __restrict__ cnt) {
  if (blockIdx.x == 0 && threadIdx.x == 0) {
    accs[0] = 0.f; accs[1] = 0.f; *cnt = 0u;
  }

  const int row  = blockIdx.x * 4 + (threadIdx.x >> 6);
  const int lane = threadIdx.x & 63;
  const bool isx = row < NX;
  const float* src = isx ? (x + (size_t)row * DD) : (xp + (size_t)(row - NX) * DD);
  float2 v = ((const float2*)src)[lane];
  float ss = v.x * v.x + v.y * v.y;

  float ssp = 0.f, d = 0.f;
  if (isx) {
    const int b = row & (BB - 1);
    float2 p = ((const float2*)(xp + (size_t)b * DD))[lane];
    ssp = p.x * p.x + p.y * p.y;
    d = v.x * p.x + v.y * p.y;
  }
  // wave-wide sums (all lanes get result)
  ss  = row16_sum(ss);  ss  += __shfl_xor(ss, 16, 64);  ss  += __shfl_xor(ss, 32, 64);
  if (isx) {
    ssp = row16_sum(ssp); ssp += __shfl_xor(ssp, 16, 64); ssp += __shfl_xor(ssp, 32, 64);
    d   = row16_sum(d);   d   += __shfl_xor(d, 16, 64);   d   += __shfl_xor(d, 32, 64);
  }
  const float rn = rsqrtf(ss);           // pure normalizer (for pos)
  const float rns = rn * SQRT10;         // scaled for znb8
  const int pk = __builtin_amdgcn_cvt_pk_fp8_f32(v.x * rns, v.y * rns, 0, false);
  *(uint16_t*)(znb8 + (size_t)row * DD + lane * 2) = (uint16_t)(pk & 0xffff);
  if (isx && lane == 0) pos[row] = d * rn * rsqrtf(ssp);
}

// K2: upper-triangle 128x128 tiles of 10*sim = Zs*Zs^T via MX-scaled fp8 MFMA
// (mfma_scale_f32_16x16x128_f8f6f4, fmt=e4m3, unit scales 0x7F -> x1.0).
// LDS staging via global_load_lds + XOR swizzle (R2 lesson: staging amortizes
// L2 latency; direct frag loads cost +10 us).
// NO GLOBAL ATOMICS (R3 post-mortem: ~1.05M device-scope atomicAdd RMWs onto
// 512 cache lines serialized at the coherency point = WRITE_SIZE 10.4 MB and
// the dominant ~30+ us of every prior variant, with MfmaUtil/VALU/HBM all
// idle). Instead: LDS-combine the 4 waves' row/col partials and emit ONE
// coalesced 1 KB plain store per block into scratch[t][256]
// (row-half [0,128): panel bi; col-half [128,256): panel bj, unread if diag).
// K3 gathers. NO fences (R1 lesson).
__global__ __launch_bounds__(256, 4) void mp_simexp(const uint8_t* __restrict__ znb8,
                                                    float* __restrict__ scratch) {
  __shared__ uint8_t Asmem[128 * 128];
  __shared__ uint8_t Bsmem[128 * 128];

  // Triangular decode: block t -> (bi, bj), bi <= bj.
  const int t = blockIdx.x;
  int bi = (int)((129.0f - sqrtf(16641.0f - 8.0f * (float)t)) * 0.5f);
  #define FCUM(r) ((r) * 64 - ((r) * ((r) - 1)) / 2)
  while (bi > 0 && FCUM(bi) > t) --bi;
  while (FCUM(bi + 1) <= t) ++bi;
  const int bj = bi + (t - FCUM(bi));
  const bool diag = (bi == bj);

  const int tid  = threadIdx.x;
  const int wave = tid >> 6, lane = tid & 63;
  const int lhi = lane >> 4, llo = lane & 15;

  const uint8_t* gA = znb8 + (size_t)bi * 128 * DD;
  const uint8_t* gB = znb8 + (size_t)bj * 128 * DD;

  // Stage tiles (16 KB each), 16 B/lane. Each wave-instr covers 8 rows
  // (128 B/row); lane l -> row c*8+(l>>3), 16-B pair p = (l&7)^(row&7)
  // (global source swizzled; LDS dest stays lane-contiguous). Diag: A only.
  #pragma unroll
  for (int tc = 0; tc < 4; ++tc) {
    const int c = wave * 4 + tc;
    const int row = c * 8 + (lane >> 3);
    const int p = (lane & 7) ^ (row & 7);
    const int roff = row * DD + p * 16;
    __builtin_amdgcn_global_load_lds(GLOBAL_AS(gA + roff), LDS_AS(&Asmem[c * 1024]), 16, 0, 0);
    if (!diag)
      __builtin_amdgcn_global_load_lds(GLOBAL_AS(gB + roff), LDS_AS(&Bsmem[c * 1024]), 16, 0, 0);
  }
  __syncthreads();
  const uint8_t* Bs = diag ? Asmem : Bsmem;

  // 2x2 wave grid; each wave computes a 64x64 subtile = 4x4 MFMA tiles,
  // one K=128 MFMA each. Frag: lane(llo=row, lhi): 32 contiguous K bytes at
  // lhi*32 = swizzled 16-B pairs (2*lhi)^(row&7), (2*lhi+1)^(row&7).
  // K-permutation invariance: A/B frags use identical addressing from
  // identically-laid-out tiles, so internal K ordering cancels in Z*Z^T.
  const int wr = wave >> 1, wc = wave & 1;
  floatx4 acc[4][4] = {};
  intx8 bfrag[4];
  #pragma unroll
  for (int c = 0; c < 4; ++c) {
    const int row = wc * 64 + c * 16 + llo;
    const uint8_t* base = Bs + row * DD;
    intx4 lo = *(const intx4*)(base + (((2 * lhi)     ^ (row & 7)) << 4));
    intx4 hi = *(const intx4*)(base + (((2 * lhi + 1) ^ (row & 7)) << 4));
    bfrag[c] = intx8{lo.x, lo.y, lo.z, lo.w, hi.x, hi.y, hi.z, hi.w};
  }
  #pragma unroll
  for (int r = 0; r < 4; ++r) {
    const int row = wr * 64 + r * 16 + llo;
    const uint8_t* base = Asmem + row * DD;
    intx4 lo = *(const intx4*)(base + (((2 * lhi)     ^ (row & 7)) << 4));
    intx4 hi = *(const intx4*)(base + (((2 * lhi + 1) ^ (row & 7)) << 4));
    intx8 afrag = intx8{lo.x, lo.y, lo.z, lo.w, hi.x, hi.y, hi.z, hi.w};
    #pragma unroll
    for (int c = 0; c < 4; ++c)
      acc[r][c] = __builtin_amdgcn_mfma_scale_f32_16x16x128_f8f6f4(
          afrag, bfrag[c], acc[r][c], 0, 0, 0, 0x7F7F7F7F, 0, 0x7F7F7F7F);
  }

  // Epilogue: e = exp(acc) (acc is already 10*cos); diag masked on the 64
  // diagonal blocks only (uniform branch). Row sums + col sums.
  // C/D layout: col = lane&15, row = (lane>>4)*4 + reg.
  float rowacc[4][4];
  #pragma unroll
  for (int r = 0; r < 4; ++r)
    #pragma unroll
    for (int j = 0; j < 4; ++j) rowacc[r][j] = 0.f;
  float colacc[4] = {0.f, 0.f, 0.f, 0.f};

  if (diag) {
    #pragma unroll
    for (int r = 0; r < 4; ++r) {
      #pragma unroll
      for (int c = 0; c < 4; ++c) {
        const int col = wc * 64 + c * 16 + llo;
        #pragma unroll
        for (int j = 0; j < 4; ++j) {
          const int row = wr * 64 + r * 16 + lhi * 4 + j;
          float e = __expf(acc[r][c][j]);
          if (row == col) e = 0.f;
          rowacc[r][j] += e;
          colacc[c] += e;
        }
      }
    }
  } else {
    #pragma unroll
    for (int r = 0; r < 4; ++r) {
      #pragma unroll
      for (int c = 0; c < 4; ++c) {
        #pragma unroll
        for (int j = 0; j < 4; ++j) {
          float e = __expf(acc[r][c][j]);
          rowacc[r][j] += e;
          colacc[c] += e;
        }
      }
    }
  }

  // LDS-combine partials (reuse Asmem; barrier: all frag ds_reads are done).
  __syncthreads();
  float* lds_r = (float*)Asmem;            // [256]: [wc][row 0..127]
  float* lds_c = (float*)(Asmem + 1024);   // [256]: [wr][col 0..127]
  #pragma unroll
  for (int r = 0; r < 4; ++r) {
    #pragma unroll
    for (int j = 0; j < 4; ++j) {
      float s = row16_sum(rowacc[r][j]);   // full row sum over wave's 64 cols
      if (llo == j) lds_r[wc * 128 + wr * 64 + r * 16 + lhi * 4 + j] = s;
    }
  }
  #pragma unroll
  for (int c = 0; c < 4; ++c) {
    float s = colacc[c];
    s += __shfl_xor(s, 16, 64);
    s += __shfl_xor(s, 32, 64);             // full col sum over wave's 64 rows
    if (lhi == 0) lds_c[wr * 128 + wc * 64 + c * 16 + llo] = s;
  }
  __syncthreads();

  // One coalesced 1 KB store: [0,128) = row partials (panel bi),
  // [128,256) = col partials (panel bj; never read by K3 when diag).
  float outv;
  if (tid < 128) outv = lds_r[tid] + lds_r[128 + tid];
  else           outv = lds_c[tid - 128] + lds_c[tid];
  scratch[(size_t)t * 256 + tid] = outv;
}

// K3: gather-reduce + fused tail. One block per 128-row panel P (64 blocks,
// 128 threads). Row z = P*128+idx receives exactly 64 partials:
//   row-halves of blocks (P, bj), bj=P..63  -> contiguous t = FCUM(P)+k
//   col-halves of blocks (bi, P), bi=0..P-1 -> t = FCUM(bi)+(P-bi)
// Then log, block-reduce, 2 atomicAdds; last block (relaxed counter, no
// fences — 64 blocks, negligible) emits the final scalar.
__global__ __launch_bounds__(128) void mp_reduce(const float* __restrict__ scratch,
                                                 const float* __restrict__ pos,
                                                 float* __restrict__ accs,
                                                 uint32_t* __restrict__ cnt,
                                                 float* __restrict__ out) {
  const int P = blockIdx.x;
  const int idx = threadIdx.x;             // 0..127
  const int nrow = NPAN - P;
  const int base = P * NPAN - (P * (P - 1)) / 2;  // FCUM(P)

  float s = 0.f;
  #pragma unroll 4
  for (int k = 0; k < NPAN; ++k) {         // k<nrow uniform per block
    int off;
    if (k < nrow) {
      off = (base + k) * 256 + idx;                        // row-half (P,P+k)
    } else {
      const int b2 = k - nrow;                             // bi in [0,P)
      const int T = b2 * NPAN - (b2 * (b2 - 1)) / 2 + (P - b2);
      off = T * 256 + 128 + idx;                           // col-half (bi,P)
    }
    s += scratch[off];
  }
  float l = logf(s);
  float p = (P < 48) ? pos[P * 128 + idx] : 0.f;  // panels 0..47 are x-rows
  #pragma unroll
  for (int m = 1; m < 64; m <<= 1) {
    l += __shfl_xor(l, m, 64);
    p += __shfl_xor(p, m, 64);
  }
  __shared__ float rl2[2], rp2[2];
  __shared__ int lastflag;
  if ((idx & 63) == 0) { rl2[idx >> 6] = l; rp2[idx >> 6] = p; }
  __syncthreads();
  if (idx == 0) {
    atomicAdd(&accs[0], rl2[0] + rl2[1]);
    atomicAdd(&accs[1], rp2[0] + rp2[1]);
  }
  asm volatile("s_waitcnt vmcnt(0)" ::: "memory");  // this wave's atomics acked
  __syncthreads();
  if (idx == 0) {
    uint32_t old = __hip_atomic_fetch_add(cnt, 1u, __ATOMIC_RELAXED,
                                          __HIP_MEMORY_SCOPE_AGENT);
    lastflag = (old == NPAN - 1);
  }
  __syncthreads();
  if (lastflag && idx == 0) {
    float S  = __hip_atomic_load(&accs[0], __ATOMIC_RELAXED, __HIP_MEMORY_SCOPE_AGENT);
    float Pp = __hip_atomic_load(&accs[1], __ATOMIC_RELAXED, __HIP_MEMORY_SCOPE_AGENT);
    const float loss_neg = S / (float)NTOT + LOG_SUB_FRAC;
    const float loss_pos = Pp * (10.0f / (float)NX);  // WEIGHT*(1/TEMP)/(B*NPOS)
    out[0] = loss_neg - loss_pos;
  }
}

extern "C" void kernel_launch(void* const* d_in, const int* in_sizes, int n_in,
                              void* d_out, int out_size, void* d_ws, size_t ws_size,
                              hipStream_t stream) {
  const float* x  = (const float*)d_in[0];   // [6144, 128] f32
  const float* xp = (const float*)d_in[1];   // [2048, 128] f32
  float* out = (float*)d_out;                // scalar f32

  char* ws = (char*)d_ws;
  uint8_t* znb8  = (uint8_t*)ws;                                   // 1 MB
  float* pos     = (float*)(ws + (1u << 20));                      // 24 KB (pad 32K)
  float* scratch = (float*)(ws + (1u << 20) + (32u << 10));        // 2080*1KB
  float* accs    = (float*)(ws + (1u << 20) + (32u << 10) + NBLK * 1024u);
  uint32_t* cnt  = (uint32_t*)(ws + (1u << 20) + (32u << 10) + NBLK * 1024u + 8u);

  mp_norm<<<NTOT / 4, 256, 0, stream>>>(x, xp, znb8, pos, accs, cnt);
  mp_simexp<<<NBLK, 256, 0, stream>>>(znb8, scratch);
  mp_reduce<<<NPAN, 128, 0, stream>>>(scratch, pos, accs, cnt, out);
}

// Round 5
// 82.129 us; speedup vs baseline: 1.2276x; 1.0020x over previous
//
#include <hip/hip_runtime.h>
#include <stdint.h>

// Problem constants
#define NTOT 8192   // B*(1+NPOS)
#define DD   128    // feature dim
#define BB   2048   // batch
#define NX   6144   // NPOS*B rows of x
// loss_neg subsample correction: log(4096/8191)
#define LOG_SUB_FRAC (-0.6930251f)
#define SQRT10 3.16227766017f
#define NBLK 2080   // 64*65/2 upper-tri tiles (scratch slots)
#define NCHK 1056   // sum over rows bi of ceil((64-bi)/2): 2-tile chunks
#define NPAN 64     // 128-row panels

typedef __attribute__((ext_vector_type(4))) float floatx4;  // MFMA C/D
typedef __attribute__((ext_vector_type(4))) int   intx4;
typedef __attribute__((ext_vector_type(8))) int   intx8;    // 32 B fp8 frag

#define GLOBAL_AS(p) ((const __attribute__((address_space(1))) void*)(p))
#define LDS_AS(p)    ((__attribute__((address_space(3))) void*)(p))

// DPP add: s + permuted(s). Row = 16 lanes on CDNA.
template <int CTRL>
__device__ __forceinline__ float dpp_add(float s) {
  return s + __int_as_float(
      __builtin_amdgcn_update_dpp(0, __float_as_int(s), CTRL, 0xF, 0xF, true));
}
// Sum across a 16-lane row (result in all 16 lanes): xor1, xor2, ror4, ror8.
__device__ __forceinline__ float row16_sum(float s) {
  s = dpp_add<0xB1>(s);   // quad_perm [1,0,3,2]
  s = dpp_add<0x4E>(s);   // quad_perm [2,3,0,1]
  s = dpp_add<0x124>(s);  // row_ror:4
  s = dpp_add<0x128>(s);  // row_ror:8
  return s;
}

// K1: L2-normalize rows of z = [x ; x_pair], scale by sqrt(10) (folds 1/TEMP
// into the MFMA so sim accumulates 10*cos directly) -> fp8 e4m3 (OCP).
// Fused positive dots (pure f32, unscaled). One wave per row.
// Zero-inits the K3 accumulators/counter (stream-ordered flush at boundary).
__global__ __launch_bounds__(256) void mp_norm(const float* __restrict__ x,
                                               const float* __restrict__ xp,
                                               uint8_t* __restrict__ znb8,
                                               float* __restrict__ pos,
                                               float* __restrict__ accs,
                                               uint32_t* __restrict__ cnt) {
  if (blockIdx.x == 0 && threadIdx.x == 0) {
    accs[0] = 0.f; accs[1] = 0.f; *cnt = 0u;
  }

  const int row  = blockIdx.x * 4 + (threadIdx.x >> 6);
  const int lane = threadIdx.x & 63;
  const bool isx = row < NX;
  const float* src = isx ? (x + (size_t)row * DD) : (xp + (size_t)(row - NX) * DD);
  float2 v = ((const float2*)src)[lane];
  float ss = v.x * v.x + v.y * v.y;

  float ssp = 0.f, d = 0.f;
  if (isx) {
    const int b = row & (BB - 1);
    float2 p = ((const float2*)(xp + (size_t)b * DD))[lane];
    ssp = p.x * p.x + p.y * p.y;
    d = v.x * p.x + v.y * p.y;
  }
  // wave-wide sums (all lanes get result)
  ss  = row16_sum(ss);  ss  += __shfl_xor(ss, 16, 64);  ss  += __shfl_xor(ss, 32, 64);
  if (isx) {
    ssp = row16_sum(ssp); ssp += __shfl_xor(ssp, 16, 64); ssp += __shfl_xor(ssp, 32, 64);
    d   = row16_sum(d);   d   += __shfl_xor(d, 16, 64);   d   += __shfl_xor(d, 32, 64);
  }
  const float rn = rsqrtf(ss);           // pure normalizer (for pos)
  const float rns = rn * SQRT10;         // scaled for znb8
  const int pk = __builtin_amdgcn_cvt_pk_fp8_f32(v.x * rns, v.y * rns, 0, false);
  *(uint16_t*)(znb8 + (size_t)row * DD + lane * 2) = (uint16_t)(pk & 0xffff);
  if (isx && lane == 0) pos[row] = d * rn * rsqrtf(ssp);
}

// K2: upper-triangle 128x128 tiles of 10*sim = Zs*Zs^T via MX-scaled fp8 MFMA
// (mfma_scale_f32_16x16x128_f8f6f4, fmt=e4m3, unit scales 0x7F -> x1.0).
// R4 post-mortem: per-block {stage -> vmcnt(0)+barrier drain -> short
// compute} left the CU idle most of each block's life (K2 ~20us vs ~8 ideal).
// This round: 2-TILE CHUNKS — each block takes two consecutive tiles of one
// triangle row (same A panel): stage A + B0 + B1 (<=48 KB) with ONE drain,
// then 128 MFMAs + 2 epilogues. Staged bytes 66->50 MB, drains 2080->1056,
// row partials accumulate in registers across both tiles (stored in tile0's
// scratch row-half; tile1's row-half zeroed -> K3 gather unchanged).
// No global atomics (R3 lesson), no fences (R1 lesson), LDS staging kept
// (R2 lesson). LDS 51 KB -> 3 blocks/CU.
__global__ __launch_bounds__(256, 3) void mp_simexp(const uint8_t* __restrict__ znb8,
                                                    float* __restrict__ scratch) {
  __shared__ uint8_t Abuf[128 * 128];
  __shared__ uint8_t Bbuf[2][128 * 128];
  __shared__ float comb[3 * 256];   // [0,256)=row halves, [256,512)=col t0, [512,768)=col t1

  // Chunk decode: block p -> row bi, first tile bj0 = bi + 2*(chunk idx).
  // Row bi has ceil((64-bi)/2) = (65-bi)>>1 chunks.
  int p = blockIdx.x, bi = 0, nch = 32;
  while (p >= nch) { p -= nch; ++bi; nch = (65 - bi) >> 1; }
  const int bj0 = bi + p * 2;
  const int nt = ((64 - bj0) >= 2) ? 2 : 1;     // tiles in this chunk
  const bool d0 = (bj0 == bi);                  // first tile is diagonal
  #define FCUM(r) ((r) * 64 - ((r) * ((r) - 1)) / 2)
  const int t0 = FCUM(bi) + (bj0 - bi);         // scratch slot of tile 0

  const int tid  = threadIdx.x;
  const int wave = tid >> 6, lane = tid & 63;
  const int lhi = lane >> 4, llo = lane & 15;
  const int wr = wave >> 1, wc = wave & 1;

  // Stage A and the non-diag B tiles: 16 B/lane, each wave-instr covers 8
  // rows (128 B/row); lane l -> row c*8+(l>>3), 16-B pair pq=(l&7)^(row&7)
  // (global source swizzled; LDS dest lane-contiguous). ONE drain for all.
  const uint8_t* gA = znb8 + (size_t)bi * 128 * DD;
  #pragma unroll
  for (int tc = 0; tc < 4; ++tc) {
    const int c = wave * 4 + tc;
    const int row = c * 8 + (lane >> 3);
    const int pq = (lane & 7) ^ (row & 7);
    const int roff = row * DD + pq * 16;
    __builtin_amdgcn_global_load_lds(GLOBAL_AS(gA + roff), LDS_AS(&Abuf[c * 1024]), 16, 0, 0);
    if (!d0)
      __builtin_amdgcn_global_load_lds(GLOBAL_AS(znb8 + (size_t)bj0 * 128 * DD + roff),
                                       LDS_AS(&Bbuf[0][c * 1024]), 16, 0, 0);
    if (nt == 2)
      __builtin_amdgcn_global_load_lds(GLOBAL_AS(znb8 + (size_t)(bj0 + 1) * 128 * DD + roff),
                                       LDS_AS(&Bbuf[1][c * 1024]), 16, 0, 0);
  }
  __syncthreads();

  // Row partials persist across both tiles (same A panel / same rows).
  float rowacc[4][4];
  #pragma unroll
  for (int r = 0; r < 4; ++r)
    #pragma unroll
    for (int j = 0; j < 4; ++j) rowacc[r][j] = 0.f;

  for (int s = 0; s < nt; ++s) {
    const bool diag = (s == 0) && d0;
    const uint8_t* Bs = diag ? Abuf : Bbuf[s];

    // Frag: lane(llo=row, lhi): 32 contiguous K bytes at lhi*32 = swizzled
    // 16-B pairs (2*lhi)^(row&7), (2*lhi+1)^(row&7). K-permutation
    // invariance: identical addressing for A/B frags cancels in Z*Z^T.
    intx8 bfrag[4];
    #pragma unroll
    for (int c = 0; c < 4; ++c) {
      const int row = wc * 64 + c * 16 + llo;
      const uint8_t* base = Bs + row * DD;
      intx4 lo = *(const intx4*)(base + (((2 * lhi)     ^ (row & 7)) << 4));
      intx4 hi = *(const intx4*)(base + (((2 * lhi + 1) ^ (row & 7)) << 4));
      bfrag[c] = intx8{lo.x, lo.y, lo.z, lo.w, hi.x, hi.y, hi.z, hi.w};
    }
    floatx4 acc[4][4] = {};
    #pragma unroll
    for (int r = 0; r < 4; ++r) {
      const int row = wr * 64 + r * 16 + llo;
      const uint8_t* base = Abuf + row * DD;
      intx4 lo = *(const intx4*)(base + (((2 * lhi)     ^ (row & 7)) << 4));
      intx4 hi = *(const intx4*)(base + (((2 * lhi + 1) ^ (row & 7)) << 4));
      intx8 afrag = intx8{lo.x, lo.y, lo.z, lo.w, hi.x, hi.y, hi.z, hi.w};
      #pragma unroll
      for (int c = 0; c < 4; ++c)
        acc[r][c] = __builtin_amdgcn_mfma_scale_f32_16x16x128_f8f6f4(
            afrag, bfrag[c], acc[r][c], 0, 0, 0, 0x7F7F7F7F, 0, 0x7F7F7F7F);
    }

    // e = exp(acc) (acc is already 10*cos); diag masked (uniform branch).
    // C/D layout: col = lane&15, row = (lane>>4)*4 + reg.
    float colacc[4] = {0.f, 0.f, 0.f, 0.f};
    if (diag) {
      #pragma unroll
      for (int r = 0; r < 4; ++r) {
        #pragma unroll
        for (int c = 0; c < 4; ++c) {
          const int col = wc * 64 + c * 16 + llo;
          #pragma unroll
          for (int j = 0; j < 4; ++j) {
            const int row = wr * 64 + r * 16 + lhi * 4 + j;
            float e = __expf(acc[r][c][j]);
            if (row == col) e = 0.f;
            rowacc[r][j] += e;
            colacc[c] += e;
          }
        }
      }
    } else {
      #pragma unroll
      for (int r = 0; r < 4; ++r) {
        #pragma unroll
        for (int c = 0; c < 4; ++c) {
          #pragma unroll
          for (int j = 0; j < 4; ++j) {
            float e = __expf(acc[r][c][j]);
            rowacc[r][j] += e;
            colacc[c] += e;
          }
        }
      }
    }
    // Col partials for this tile -> comb[256*(1+s)] (diag tile's col-half
    // is never read by K3; writing it is harmless).
    #pragma unroll
    for (int c = 0; c < 4; ++c) {
      float sc = colacc[c];
      sc += __shfl_xor(sc, 16, 64);
      sc += __shfl_xor(sc, 32, 64);          // full col sum over wave's 64 rows
      if (lhi == 0) comb[256 * (1 + s) + wr * 128 + wc * 64 + c * 16 + llo] = sc;
    }
  }

  // Row partials (whole chunk) -> comb[0..256).
  #pragma unroll
  for (int r = 0; r < 4; ++r) {
    #pragma unroll
    for (int j = 0; j < 4; ++j) {
      float s = row16_sum(rowacc[r][j]);     // row sum over wave's 64 cols (x nt tiles)
      if (llo == j) comb[wc * 128 + wr * 64 + r * 16 + lhi * 4 + j] = s;
    }
  }
  __syncthreads();

  // Coalesced stores. Row-half of t0 = chunk row partials; t1 row-half = 0
  // (keeps K3's gather unchanged). Col-halves per tile.
  if (tid < 128) {
    scratch[(size_t)t0 * 256 + tid] = comb[tid] + comb[128 + tid];
    if (nt == 2) scratch[(size_t)(t0 + 1) * 256 + tid] = 0.f;
  } else {
    const int i = tid - 128;
    scratch[(size_t)t0 * 256 + 128 + i] = comb[256 + i] + comb[256 + 128 + i];
    if (nt == 2)
      scratch[(size_t)(t0 + 1) * 256 + 128 + i] = comb[512 + i] + comb[512 + 128 + i];
  }
}

// K3: gather-reduce + fused tail. One block per 128-row panel P (64 blocks,
// 128 threads). Row z = P*128+idx receives exactly 64 partials:
//   row-halves of blocks (P, bj), bj=P..63  -> contiguous t = FCUM(P)+k
//   col-halves of blocks (bi, P), bi=0..P-1 -> t = FCUM(bi)+(P-bi)
// Then log, block-reduce, 2 atomicAdds; last block (relaxed counter, no
// fences — 64 blocks, negligible) emits the final scalar.
__global__ __launch_bounds__(128) void mp_reduce(const float* __restrict__ scratch,
                                                 const float* __restrict__ pos,
                                                 float* __restrict__ accs,
                                                 uint32_t* __restrict__ cnt,
                                                 float* __restrict__ out) {
  const int P = blockIdx.x;
  const int idx = threadIdx.x;             // 0..127
  const int nrow = NPAN - P;
  const int base = P * NPAN - (P * (P - 1)) / 2;  // FCUM(P)

  float s = 0.f;
  #pragma unroll 4
  for (int k = 0; k < NPAN; ++k) {         // k<nrow uniform per block
    int off;
    if (k < nrow) {
      off = (base + k) * 256 + idx;                        // row-half (P,P+k)
    } else {
      const int b2 = k - nrow;                             // bi in [0,P)
      const int T = b2 * NPAN - (b2 * (b2 - 1)) / 2 + (P - b2);
      off = T * 256 + 128 + idx;                           // col-half (bi,P)
    }
    s += scratch[off];
  }
  float l = logf(s);
  float p = (P < 48) ? pos[P * 128 + idx] : 0.f;  // panels 0..47 are x-rows
  #pragma unroll
  for (int m = 1; m < 64; m <<= 1) {
    l += __shfl_xor(l, m, 64);
    p += __shfl_xor(p, m, 64);
  }
  __shared__ float rl2[2], rp2[2];
  __shared__ int lastflag;
  if ((idx & 63) == 0) { rl2[idx >> 6] = l; rp2[idx >> 6] = p; }
  __syncthreads();
  if (idx == 0) {
    atomicAdd(&accs[0], rl2[0] + rl2[1]);
    atomicAdd(&accs[1], rp2[0] + rp2[1]);
  }
  asm volatile("s_waitcnt vmcnt(0)" ::: "memory");  // this wave's atomics acked
  __syncthreads();
  if (idx == 0) {
    uint32_t old = __hip_atomic_fetch_add(cnt, 1u, __ATOMIC_RELAXED,
                                          __HIP_MEMORY_SCOPE_AGENT);
    lastflag = (old == NPAN - 1);
  }
  __syncthreads();
  if (lastflag && idx == 0) {
    float S  = __hip_atomic_load(&accs[0], __ATOMIC_RELAXED, __HIP_MEMORY_SCOPE_AGENT);
    float Pp = __hip_atomic_load(&accs[1], __ATOMIC_RELAXED, __HIP_MEMORY_SCOPE_AGENT);
    const float loss_neg = S / (float)NTOT + LOG_SUB_FRAC;
    const float loss_pos = Pp * (10.0f / (float)NX);  // WEIGHT*(1/TEMP)/(B*NPOS)
    out[0] = loss_neg - loss_pos;
  }
}

extern "C" void kernel_launch(void* const* d_in, const int* in_sizes, int n_in,
                              void* d_out, int out_size, void* d_ws, size_t ws_size,
                              hipStream_t stream) {
  const float* x  = (const float*)d_in[0];   // [6144, 128] f32
  const float* xp = (const float*)d_in[1];   // [2048, 128] f32
  float* out = (float*)d_out;                // scalar f32

  char* ws = (char*)d_ws;
  uint8_t* znb8  = (uint8_t*)ws;                                   // 1 MB
  float* pos     = (float*)(ws + (1u << 20));                      // 24 KB (pad 32K)
  float* scratch = (float*)(ws + (1u << 20) + (32u << 10));        // 2080*1KB
  float* accs    = (float*)(ws + (1u << 20) + (32u << 10) + NBLK * 1024u);
  uint32_t* cnt  = (uint32_t*)(ws + (1u << 20) + (32u << 10) + NBLK * 1024u + 8u);

  mp_norm<<<NTOT / 4, 256, 0, stream>>>(x, xp, znb8, pos, accs, cnt);
  mp_simexp<<<NCHK, 256, 0, stream>>>(znb8, scratch);
  mp_reduce<<<NPAN, 128, 0, stream>>>(scratch, pos, accs, cnt, out);
}